// Round 9
// baseline (305.246 us; speedup 1.0000x reference)
//
#include <hip/hip_runtime.h>
#include <hip/hip_bf16.h>

#define NN 2048
#define BB 8
#define FD 256
#define NEG_SLOPE 0.2f
#define EPSV 1e-7f

typedef __bf16 bf16x8 __attribute__((ext_vector_type(8)));
typedef __bf16 bf16x4 __attribute__((ext_vector_type(4)));
typedef float f32x4 __attribute__((ext_vector_type(4)));

// ---------------- K1: WT[o][f] = bf16(W[f][o]) ----------------
__global__ __launch_bounds__(256) void k1_prep(const float* __restrict__ W,
                                               __bf16* __restrict__ WT) {
    int idx = blockIdx.x * 256 + threadIdx.x;   // 256 blocks
    int o = idx >> 8, f = idx & 255;
    WT[idx] = (__bf16)W[f * FD + o];
}

// ---------------- K2: Wh = x @ W (bf16 MFMA) + fused s_src/s_dst scores --------
__global__ __launch_bounds__(256) void k2_whgemm(const float* __restrict__ x,
                                                 const __bf16* __restrict__ WT,
                                                 const float* __restrict__ a_w,
                                                 float* __restrict__ Wh,
                                                 float* __restrict__ s_src,
                                                 float* __restrict__ s_dst) {
    const int wave = threadIdx.x >> 6;
    const int lane = threadIdx.x & 63;
    const int row0 = blockIdx.x * 32 + (wave >> 1) * 16;
    const int ohalf = (wave & 1) * 128;
    const int m = lane & 15;
    const int quad = lane >> 4;
    const int row = row0 + m;
    const float* xrow = x + (size_t)row * FD + quad * 8;

    f32x4 acc[8];
#pragma unroll
    for (int n = 0; n < 8; ++n) acc[n] = (f32x4){0.f, 0.f, 0.f, 0.f};

    for (int k0 = 0; k0 < FD; k0 += 32) {
        float4 xa = *(const float4*)(xrow + k0);
        float4 xb = *(const float4*)(xrow + k0 + 4);
        bf16x8 af;
        af[0] = (__bf16)xa.x; af[1] = (__bf16)xa.y; af[2] = (__bf16)xa.z; af[3] = (__bf16)xa.w;
        af[4] = (__bf16)xb.x; af[5] = (__bf16)xb.y; af[6] = (__bf16)xb.z; af[7] = (__bf16)xb.w;
#pragma unroll
        for (int n = 0; n < 8; ++n) {
            int o = ohalf + n * 16 + m;
            bf16x8 bf = *(const bf16x8*)(WT + o * FD + k0 + quad * 8);
            acc[n] = __builtin_amdgcn_mfma_f32_16x16x32_bf16(af, bf, acc[n], 0, 0, 0);
        }
    }
#pragma unroll
    for (int n = 0; n < 8; ++n) {
        int o = ohalf + n * 16 + m;
#pragma unroll
        for (int r = 0; r < 4; ++r) {
            Wh[(size_t)(row0 + quad * 4 + r) * FD + o] = acc[n][r];
        }
    }

    float psrc[4] = {0.f, 0.f, 0.f, 0.f};
    float pdst[4] = {0.f, 0.f, 0.f, 0.f};
#pragma unroll
    for (int n = 0; n < 8; ++n) {
        int o = ohalf + n * 16 + m;
        float awS = a_w[o], awD = a_w[FD + o];
#pragma unroll
        for (int r = 0; r < 4; ++r) {
            psrc[r] += acc[n][r] * awS;
            pdst[r] += acc[n][r] * awD;
        }
    }
#pragma unroll
    for (int off = 1; off <= 8; off <<= 1) {
#pragma unroll
        for (int r = 0; r < 4; ++r) {
            psrc[r] += __shfl_xor(psrc[r], off, 64);
            pdst[r] += __shfl_xor(pdst[r], off, 64);
        }
    }
    __shared__ float sS[2][2][16], sD[2][2][16];
    if (m == 0) {
        int rp = wave >> 1, oh = wave & 1;
#pragma unroll
        for (int r = 0; r < 4; ++r) {
            sS[rp][oh][quad * 4 + r] = psrc[r];
            sD[rp][oh][quad * 4 + r] = pdst[r];
        }
    }
    __syncthreads();
    if (threadIdx.x < 32) {
        int rp = threadIdx.x >> 4, idx = threadIdx.x & 15;
        int orow = blockIdx.x * 32 + rp * 16 + idx;
        s_src[orow] = sS[rp][0][idx] + sS[rp][1][idx];
        s_dst[orow] = sD[rp][0][idx] + sD[rp][1][idx];
    }
}

// ---------------- K4: den_part[isp][b][j] = partial column sums ----------------
__global__ __launch_bounds__(256) void k4_den(const float* __restrict__ A,
                                              const float* __restrict__ s_src,
                                              const float* __restrict__ s_dst,
                                              const float* __restrict__ a_bp,
                                              float* __restrict__ den_part) {
    const int blk = blockIdx.x;
    const int b = blk & 7;
    const int jhalf = (blk >> 3) & 1;
    const int isp = blk >> 4;
    const int i0 = isp * 32;
    const int j = jhalf * 1024 + threadIdx.x * 4;
    __shared__ float ss[32];
    if (threadIdx.x < 32) ss[threadIdx.x] = s_src[b * NN + i0 + threadIdx.x] + a_bp[0];
    __syncthreads();
    float4 sd = *(const float4*)(s_dst + b * NN + j);
    float ax = 0.f, ay = 0.f, az = 0.f, aw = 0.f;
    const float* Ap = A + ((size_t)b * NN + i0) * NN + j;
#pragma unroll 8
    for (int i = 0; i < 32; ++i) {
        float4 a = *(const float4*)(Ap + (size_t)i * NN);
        float si = ss[i];
        float e0 = si + sd.x; e0 = e0 > 0.f ? e0 : NEG_SLOPE * e0;
        float e1 = si + sd.y; e1 = e1 > 0.f ? e1 : NEG_SLOPE * e1;
        float e2 = si + sd.z; e2 = e2 > 0.f ? e2 : NEG_SLOPE * e2;
        float e3 = si + sd.w; e3 = e3 > 0.f ? e3 : NEG_SLOPE * e3;
        ax += a.x * __expf(e0);
        ay += a.y * __expf(e1);
        az += a.z * __expf(e2);
        aw += a.w * __expf(e3);
    }
    float4 r = (float4){ax, ay, az, aw};
    *(float4*)(den_part + (size_t)isp * (BB * NN) + b * NN + j) = r;
}

// ---------------- K5: WhT[b][o][j] = bf16( Wh[b][j][o] / (sum(den_part)+eps) ) ----
__global__ __launch_bounds__(256) void k5_wht(const float* __restrict__ Wh,
                                              const float* __restrict__ den_part,
                                              __bf16* __restrict__ WhT) {
    const int b = blockIdx.z;
    const int j0 = blockIdx.x * 64;
    const int o0 = blockIdx.y * 64;
    __shared__ float tile[64][65];
    __shared__ float invd[64];
    if (threadIdx.x < 64) {
        float s = 0.f;
        const float* dp = den_part + b * NN + j0 + threadIdx.x;
#pragma unroll 8
        for (int sI = 0; sI < 64; ++sI) s += dp[(size_t)sI * (BB * NN)];
        invd[threadIdx.x] = 1.f / (s + EPSV);
    }
    __syncthreads();
    int jr = threadIdx.x >> 4, oc = (threadIdx.x & 15) * 4;
#pragma unroll
    for (int p = 0; p < 4; ++p) {
        int jj = jr + p * 16;
        float4 v = *(const float4*)(Wh + (size_t)(b * NN + j0 + jj) * FD + o0 + oc);
        float s = invd[jj];
        tile[jj][oc + 0] = v.x * s;
        tile[jj][oc + 1] = v.y * s;
        tile[jj][oc + 2] = v.z * s;
        tile[jj][oc + 3] = v.w * s;
    }
    __syncthreads();
    int ow = threadIdx.x >> 4, jc = (threadIdx.x & 15) * 4;
#pragma unroll
    for (int p = 0; p < 4; ++p) {
        int o = ow + p * 16;
        bf16x4 wv;
        wv[0] = (__bf16)tile[jc + 0][o];
        wv[1] = (__bf16)tile[jc + 1][o];
        wv[2] = (__bf16)tile[jc + 2][o];
        wv[3] = (__bf16)tile[jc + 3][o];
        *(bf16x4*)(WhT + (size_t)(b * FD + o0 + o) * NN + j0 + jc) = wv;
    }
}

// ---------------- K6F3: fused numerator GEMM, B direct-from-L2 -----------------
// 512 blocks: b = blk&7 (XCD affinity: WhT[b] 1MB + A[b] slab L2-resident),
// mt = blk>>3 (0..63), tile 32i x 256o (FULL o => each exp computed ONCE).
// 4 waves, wave w owns o-slice [w*64, w*64+64): B elements are wave-private =>
// no LDS staging for B at all; B fragments register-prefetched (E/O depth-2)
// straight from L2. LDS = only the 8KB double-buffered P tile, full 8-wide
// XOR swizzle (conflict-free). BK=64 -> 32 K-steps, 16 MFMA/wave/step.
__global__ __launch_bounds__(256) void k6f3(const float* __restrict__ A,
                                            const __bf16* __restrict__ WhT,
                                            const float* __restrict__ s_src,
                                            const float* __restrict__ s_dst,
                                            const float* __restrict__ a_bp,
                                            float* __restrict__ out) {
    __shared__ __bf16 lP[2][32 * 64];    // 4 KiB x 2
    const int blk = blockIdx.x;
    const int b = blk & 7;
    const int mt = blk >> 3;
    const int i0 = mt * 32;
    const int t = threadIdx.x;
    const int w = t >> 6, lane = t & 63;
    const int m = lane & 15, quad = lane >> 4;

    // ---- B addressing: wave-private o rows, direct 16B loads from L2 ----
    const __bf16* gB0 = WhT + ((size_t)(b * FD + w * 64 +  0 + m)) * NN + quad * 8;
    const __bf16* gB1 = WhT + ((size_t)(b * FD + w * 64 + 16 + m)) * NN + quad * 8;
    const __bf16* gB2 = WhT + ((size_t)(b * FD + w * 64 + 32 + m)) * NN + quad * 8;
    const __bf16* gB3 = WhT + ((size_t)(b * FD + w * 64 + 48 + m)) * NN + quad * 8;

    // register sets named with TRAILING stage letter (macro-paste-safe)
    bf16x8 b0aE, b1aE, b2aE, b3aE, b0bE, b1bE, b2bE, b3bE;
    bf16x8 b0aO, b1aO, b2aO, b3aO, b0bO, b1bO, b2bO, b3bO;
#define LOADB(step, S) { \
        b0a##S = *(const bf16x8*)(gB0 + (size_t)(step) * 64); \
        b1a##S = *(const bf16x8*)(gB1 + (size_t)(step) * 64); \
        b2a##S = *(const bf16x8*)(gB2 + (size_t)(step) * 64); \
        b3a##S = *(const bf16x8*)(gB3 + (size_t)(step) * 64); \
        b0b##S = *(const bf16x8*)(gB0 + (size_t)(step) * 64 + 32); \
        b1b##S = *(const bf16x8*)(gB1 + (size_t)(step) * 64 + 32); \
        b2b##S = *(const bf16x8*)(gB2 + (size_t)(step) * 64 + 32); \
        b3b##S = *(const bf16x8*)(gB3 + (size_t)(step) * 64 + 32); \
    }

    // ---- P-build: row pr = t>>3 (0..31), cols pc = (t&7)*8 (8 elems) ----
    const int pr = t >> 3;
    const int pc = (t & 7) * 8;
    const float ssr = s_src[b * NN + i0 + pr] + a_bp[0];
    const float* Ap  = A + ((size_t)(b * NN + i0 + pr)) * NN + pc;
    const float* sdp = s_dst + b * NN + pc;
    const int pdst = (((t & 7) ^ (pr & 7)) * 8);   // swizzled 16B unit
    __bf16* lProw = &lP[0][0] + pr * 64;

    float4 a0E, a1E, d0E, d1E, a0O, a1O, d0O, d1O;
#define LOADP(step, S) { \
        a0##S = *(const float4*)(Ap + (size_t)(step) * 64); \
        a1##S = *(const float4*)(Ap + (size_t)(step) * 64 + 4); \
        d0##S = *(const float4*)(sdp + (size_t)(step) * 64); \
        d1##S = *(const float4*)(sdp + (size_t)(step) * 64 + 4); \
    }
#define PB1(pv, i, av, dv) { \
        float e = ssr + dv; e = e > 0.f ? e : NEG_SLOPE * e; \
        pv[i] = (__bf16)(av * __expf(e)); }
#define PBUILD(buf, S) { \
        bf16x8 pv; \
        PB1(pv, 0, a0##S.x, d0##S.x) PB1(pv, 1, a0##S.y, d0##S.y) \
        PB1(pv, 2, a0##S.z, d0##S.z) PB1(pv, 3, a0##S.w, d0##S.w) \
        PB1(pv, 4, a1##S.x, d1##S.x) PB1(pv, 5, a1##S.y, d1##S.y) \
        PB1(pv, 6, a1##S.z, d1##S.z) PB1(pv, 7, a1##S.w, d1##S.w) \
        *(bf16x8*)(lProw + (buf) * 2048 + pdst) = pv; \
    }

    const int psw = m & 7;   // P-read row&7 == m&7 (rows mi*16+m)
#define MFMA_BLOCK(cur, S) { \
        const __bf16* lPc = &lP[cur][0]; \
        { \
            const int kof = ((0 * 4 + quad) ^ psw) * 8; \
            bf16x8 pa0 = *(const bf16x8*)(lPc + (m) * 64 + kof); \
            bf16x8 pa1 = *(const bf16x8*)(lPc + (16 + m) * 64 + kof); \
            acc[0][0] = __builtin_amdgcn_mfma_f32_16x16x32_bf16(pa0, b0a##S, acc[0][0], 0, 0, 0); \
            acc[1][0] = __builtin_amdgcn_mfma_f32_16x16x32_bf16(pa1, b0a##S, acc[1][0], 0, 0, 0); \
            acc[0][1] = __builtin_amdgcn_mfma_f32_16x16x32_bf16(pa0, b1a##S, acc[0][1], 0, 0, 0); \
            acc[1][1] = __builtin_amdgcn_mfma_f32_16x16x32_bf16(pa1, b1a##S, acc[1][1], 0, 0, 0); \
            acc[0][2] = __builtin_amdgcn_mfma_f32_16x16x32_bf16(pa0, b2a##S, acc[0][2], 0, 0, 0); \
            acc[1][2] = __builtin_amdgcn_mfma_f32_16x16x32_bf16(pa1, b2a##S, acc[1][2], 0, 0, 0); \
            acc[0][3] = __builtin_amdgcn_mfma_f32_16x16x32_bf16(pa0, b3a##S, acc[0][3], 0, 0, 0); \
            acc[1][3] = __builtin_amdgcn_mfma_f32_16x16x32_bf16(pa1, b3a##S, acc[1][3], 0, 0, 0); \
        } \
        { \
            const int kof = ((1 * 4 + quad) ^ psw) * 8; \
            bf16x8 pa0 = *(const bf16x8*)(lPc + (m) * 64 + kof); \
            bf16x8 pa1 = *(const bf16x8*)(lPc + (16 + m) * 64 + kof); \
            acc[0][0] = __builtin_amdgcn_mfma_f32_16x16x32_bf16(pa0, b0b##S, acc[0][0], 0, 0, 0); \
            acc[1][0] = __builtin_amdgcn_mfma_f32_16x16x32_bf16(pa1, b0b##S, acc[1][0], 0, 0, 0); \
            acc[0][1] = __builtin_amdgcn_mfma_f32_16x16x32_bf16(pa0, b1b##S, acc[0][1], 0, 0, 0); \
            acc[1][1] = __builtin_amdgcn_mfma_f32_16x16x32_bf16(pa1, b1b##S, acc[1][1], 0, 0, 0); \
            acc[0][2] = __builtin_amdgcn_mfma_f32_16x16x32_bf16(pa0, b2b##S, acc[0][2], 0, 0, 0); \
            acc[1][2] = __builtin_amdgcn_mfma_f32_16x16x32_bf16(pa1, b2b##S, acc[1][2], 0, 0, 0); \
            acc[0][3] = __builtin_amdgcn_mfma_f32_16x16x32_bf16(pa0, b3b##S, acc[0][3], 0, 0, 0); \
            acc[1][3] = __builtin_amdgcn_mfma_f32_16x16x32_bf16(pa1, b3b##S, acc[1][3], 0, 0, 0); \
        } \
    }

    // prologue
    LOADP(0, E)
    PBUILD(0, E)        // lP[0] <- step 0
    LOADP(1, O)
    LOADB(0, E)
    LOADB(1, O)

    f32x4 acc[2][4];
#pragma unroll
    for (int mi = 0; mi < 2; ++mi)
#pragma unroll
        for (int n = 0; n < 4; ++n) acc[mi][n] = (f32x4){0.f, 0.f, 0.f, 0.f};

    for (int kt2 = 0; kt2 < 16; ++kt2) {
        const int kt = kt2 * 2;
        // ---- even step kt ----
        __syncthreads();                 // lP[0] ready
        if (kt2 < 15) LOADP(kt + 2, E)
        MFMA_BLOCK(0, E)                 // consumes bE*
        if (kt2 < 15) LOADB(kt + 2, E)   // refill bE* after use
        PBUILD(1, O)                     // lP[1] <- step kt+1
        // ---- odd step kt+1 ----
        __syncthreads();                 // lP[1] ready
        if (kt2 < 15) LOADP(kt + 3, O)
        MFMA_BLOCK(1, O)                 // consumes bO*
        if (kt2 < 15) {
            LOADB(kt + 3, O)
            PBUILD(0, E)                 // lP[0] <- step kt+2
        }
    }

#pragma unroll
    for (int mi = 0; mi < 2; ++mi)
#pragma unroll
        for (int n = 0; n < 4; ++n) {
            int o = w * 64 + n * 16 + m;
#pragma unroll
            for (int rr = 0; rr < 4; ++rr) {
                int orow = i0 + mi * 16 + quad * 4 + rr;
                out[((size_t)b * NN + orow) * FD + o] = acc[mi][n][rr];
            }
        }
#undef LOADB
#undef LOADP
#undef PB1
#undef PBUILD
#undef MFMA_BLOCK
}

extern "C" void kernel_launch(void* const* d_in, const int* in_sizes, int n_in,
                              void* d_out, int out_size, void* d_ws, size_t ws_size,
                              hipStream_t stream) {
    const float* A   = (const float*)d_in[0];
    const float* x   = (const float*)d_in[1];
    const float* W   = (const float*)d_in[2];
    const float* a_w = (const float*)d_in[3];
    const float* a_b = (const float*)d_in[4];
    float* out = (float*)d_out;

    char* ws = (char*)d_ws;
    __bf16* WT      = (__bf16*)ws;                      // 131,072 B
    float*  Wh      = (float*)(ws + 131072);            // 16,777,216 B
    __bf16* WhT     = (__bf16*)(ws + 16908288);         // 8,388,608 B
    float*  s_src   = (float*)(ws + 25296896);          // 65,536 B
    float*  s_dst   = (float*)(ws + 25362432);          // 65,536 B
    float*  den_part= (float*)(ws + 25427968);          // 4,194,304 B
                                                        // total = 29,622,272 B (proven)

    k1_prep<<<256, 256, 0, stream>>>(W, WT);
    k2_whgemm<<<512, 256, 0, stream>>>(x, WT, a_w, Wh, s_src, s_dst);
    k4_den<<<1024, 256, 0, stream>>>(A, s_src, s_dst, a_b, den_part);
    k5_wht<<<dim3(32, 4, 8), 256, 0, stream>>>(Wh, den_part, WhT);
    k6f3<<<512, 256, 0, stream>>>(A, WhT, s_src, s_dst, a_b, out);
}

// Round 10
// 292.575 us; speedup vs baseline: 1.0433x; 1.0433x over previous
//
#include <hip/hip_runtime.h>
#include <hip/hip_bf16.h>

#define NN 2048
#define BB 8
#define FD 256
#define NEG_SLOPE 0.2f
#define EPSV 1e-7f

typedef __bf16 bf16x8 __attribute__((ext_vector_type(8)));
typedef __bf16 bf16x4 __attribute__((ext_vector_type(4)));
typedef float f32x4 __attribute__((ext_vector_type(4)));

// async 16B global -> LDS (lds base wave-uniform; dest = base + lane*16)
__device__ __forceinline__ void gload16(const __bf16* g, __bf16* l) {
    __builtin_amdgcn_global_load_lds((const __attribute__((address_space(1))) unsigned int*)g,
                                     (__attribute__((address_space(3))) unsigned int*)l,
                                     16, 0, 0);
}

// ---------------- K1: WT[o][f] = bf16(W[f][o]) ----------------
__global__ __launch_bounds__(256) void k1_prep(const float* __restrict__ W,
                                               __bf16* __restrict__ WT) {
    int idx = blockIdx.x * 256 + threadIdx.x;   // 256 blocks
    int o = idx >> 8, f = idx & 255;
    WT[idx] = (__bf16)W[f * FD + o];
}

// ---------------- K2: Wh = x @ W (bf16 MFMA) + fused s_src/s_dst scores --------
__global__ __launch_bounds__(256) void k2_whgemm(const float* __restrict__ x,
                                                 const __bf16* __restrict__ WT,
                                                 const float* __restrict__ a_w,
                                                 float* __restrict__ Wh,
                                                 float* __restrict__ s_src,
                                                 float* __restrict__ s_dst) {
    const int wave = threadIdx.x >> 6;
    const int lane = threadIdx.x & 63;
    const int row0 = blockIdx.x * 32 + (wave >> 1) * 16;
    const int ohalf = (wave & 1) * 128;
    const int m = lane & 15;
    const int quad = lane >> 4;
    const int row = row0 + m;
    const float* xrow = x + (size_t)row * FD + quad * 8;

    f32x4 acc[8];
#pragma unroll
    for (int n = 0; n < 8; ++n) acc[n] = (f32x4){0.f, 0.f, 0.f, 0.f};

    for (int k0 = 0; k0 < FD; k0 += 32) {
        float4 xa = *(const float4*)(xrow + k0);
        float4 xb = *(const float4*)(xrow + k0 + 4);
        bf16x8 af;
        af[0] = (__bf16)xa.x; af[1] = (__bf16)xa.y; af[2] = (__bf16)xa.z; af[3] = (__bf16)xa.w;
        af[4] = (__bf16)xb.x; af[5] = (__bf16)xb.y; af[6] = (__bf16)xb.z; af[7] = (__bf16)xb.w;
#pragma unroll
        for (int n = 0; n < 8; ++n) {
            int o = ohalf + n * 16 + m;
            bf16x8 bf = *(const bf16x8*)(WT + o * FD + k0 + quad * 8);
            acc[n] = __builtin_amdgcn_mfma_f32_16x16x32_bf16(af, bf, acc[n], 0, 0, 0);
        }
    }
#pragma unroll
    for (int n = 0; n < 8; ++n) {
        int o = ohalf + n * 16 + m;
#pragma unroll
        for (int r = 0; r < 4; ++r) {
            Wh[(size_t)(row0 + quad * 4 + r) * FD + o] = acc[n][r];
        }
    }

    float psrc[4] = {0.f, 0.f, 0.f, 0.f};
    float pdst[4] = {0.f, 0.f, 0.f, 0.f};
#pragma unroll
    for (int n = 0; n < 8; ++n) {
        int o = ohalf + n * 16 + m;
        float awS = a_w[o], awD = a_w[FD + o];
#pragma unroll
        for (int r = 0; r < 4; ++r) {
            psrc[r] += acc[n][r] * awS;
            pdst[r] += acc[n][r] * awD;
        }
    }
#pragma unroll
    for (int off = 1; off <= 8; off <<= 1) {
#pragma unroll
        for (int r = 0; r < 4; ++r) {
            psrc[r] += __shfl_xor(psrc[r], off, 64);
            pdst[r] += __shfl_xor(pdst[r], off, 64);
        }
    }
    __shared__ float sS[2][2][16], sD[2][2][16];
    if (m == 0) {
        int rp = wave >> 1, oh = wave & 1;
#pragma unroll
        for (int r = 0; r < 4; ++r) {
            sS[rp][oh][quad * 4 + r] = psrc[r];
            sD[rp][oh][quad * 4 + r] = pdst[r];
        }
    }
    __syncthreads();
    if (threadIdx.x < 32) {
        int rp = threadIdx.x >> 4, idx = threadIdx.x & 15;
        int orow = blockIdx.x * 32 + rp * 16 + idx;
        s_src[orow] = sS[rp][0][idx] + sS[rp][1][idx];
        s_dst[orow] = sD[rp][0][idx] + sD[rp][1][idx];
    }
}

// ---------------- K4: den_part[isp][b][j] = partial column sums ----------------
__global__ __launch_bounds__(256) void k4_den(const float* __restrict__ A,
                                              const float* __restrict__ s_src,
                                              const float* __restrict__ s_dst,
                                              const float* __restrict__ a_bp,
                                              float* __restrict__ den_part) {
    const int blk = blockIdx.x;
    const int b = blk & 7;
    const int jhalf = (blk >> 3) & 1;
    const int isp = blk >> 4;
    const int i0 = isp * 32;
    const int j = jhalf * 1024 + threadIdx.x * 4;
    __shared__ float ss[32];
    if (threadIdx.x < 32) ss[threadIdx.x] = s_src[b * NN + i0 + threadIdx.x] + a_bp[0];
    __syncthreads();
    float4 sd = *(const float4*)(s_dst + b * NN + j);
    float ax = 0.f, ay = 0.f, az = 0.f, aw = 0.f;
    const float* Ap = A + ((size_t)b * NN + i0) * NN + j;
#pragma unroll 8
    for (int i = 0; i < 32; ++i) {
        float4 a = *(const float4*)(Ap + (size_t)i * NN);
        float si = ss[i];
        float e0 = si + sd.x; e0 = e0 > 0.f ? e0 : NEG_SLOPE * e0;
        float e1 = si + sd.y; e1 = e1 > 0.f ? e1 : NEG_SLOPE * e1;
        float e2 = si + sd.z; e2 = e2 > 0.f ? e2 : NEG_SLOPE * e2;
        float e3 = si + sd.w; e3 = e3 > 0.f ? e3 : NEG_SLOPE * e3;
        ax += a.x * __expf(e0);
        ay += a.y * __expf(e1);
        az += a.z * __expf(e2);
        aw += a.w * __expf(e3);
    }
    float4 r = (float4){ax, ay, az, aw};
    *(float4*)(den_part + (size_t)isp * (BB * NN) + b * NN + j) = r;
}

// ---------------- K5: WhT[b][o][j] = bf16( Wh[b][j][o] / (sum(den_part)+eps) ) ----
__global__ __launch_bounds__(256) void k5_wht(const float* __restrict__ Wh,
                                              const float* __restrict__ den_part,
                                              __bf16* __restrict__ WhT) {
    const int b = blockIdx.z;
    const int j0 = blockIdx.x * 64;
    const int o0 = blockIdx.y * 64;
    __shared__ float tile[64][65];
    __shared__ float invd[64];
    if (threadIdx.x < 64) {
        float s = 0.f;
        const float* dp = den_part + b * NN + j0 + threadIdx.x;
#pragma unroll 8
        for (int sI = 0; sI < 64; ++sI) s += dp[(size_t)sI * (BB * NN)];
        invd[threadIdx.x] = 1.f / (s + EPSV);
    }
    __syncthreads();
    int jr = threadIdx.x >> 4, oc = (threadIdx.x & 15) * 4;
#pragma unroll
    for (int p = 0; p < 4; ++p) {
        int jj = jr + p * 16;
        float4 v = *(const float4*)(Wh + (size_t)(b * NN + j0 + jj) * FD + o0 + oc);
        float s = invd[jj];
        tile[jj][oc + 0] = v.x * s;
        tile[jj][oc + 1] = v.y * s;
        tile[jj][oc + 2] = v.z * s;
        tile[jj][oc + 3] = v.w * s;
    }
    __syncthreads();
    int ow = threadIdx.x >> 4, jc = (threadIdx.x & 15) * 4;
#pragma unroll
    for (int p = 0; p < 4; ++p) {
        int o = ow + p * 16;
        bf16x4 wv;
        wv[0] = (__bf16)tile[jc + 0][o];
        wv[1] = (__bf16)tile[jc + 1][o];
        wv[2] = (__bf16)tile[jc + 2][o];
        wv[3] = (__bf16)tile[jc + 3][o];
        *(bf16x4*)(WhT + (size_t)(b * FD + o0 + o) * NN + j0 + jc) = wv;
    }
}

// ---------------- K6F: fused out = (A*exp(lrelu(e))) @ WhTn^T ------------------
// R4 structure + DEPTH-2 register prefetch for A/s_dst (E/O named reg sets,
// statically indexed 2-step unrolled loop). Best-measured config (R6: 292.7us).
__global__ __launch_bounds__(256) void k6f(const float* __restrict__ A,
                                           const __bf16* __restrict__ WhT,
                                           const float* __restrict__ s_src,
                                           const float* __restrict__ s_dst,
                                           const float* __restrict__ a_bp,
                                           float* __restrict__ out) {
    __shared__ __bf16 lP[2][64 * 64];     // 8 KiB x 2
    __shared__ __bf16 lB[2][128 * 64];    // 16 KiB x 2  (48 KiB total)
    const int blk = blockIdx.x;
    const int b = blk & 7;
    const int r_ = blk >> 3;
    const int nh = r_ & 1;
    const int mt = r_ >> 1;
    const int i0 = mt * 64;
    const int o0 = nh * 128;
    const int t = threadIdx.x;
    const int w = t >> 6, lane = t & 63;
    const int m = lane & 15, quad = lane >> 4;
    const int wr = w >> 1, wc = w & 1;

    const int srow = lane >> 3;
    const int schunk = (lane & 7) ^ srow;   // pre-swizzled source chunk
    const __bf16* gB = WhT + ((size_t)(b * FD + o0 + w * 8 + srow)) * NN + schunk * 8;

#define STAGEB(buf, step) { \
        const __bf16* gb = gB + (step) * 64; \
        gload16(gb,                   &lB[buf][0] + (w * 8) * 64); \
        gload16(gb + (size_t)32 * NN, &lB[buf][0] + (32 + w * 8) * 64); \
        gload16(gb + (size_t)64 * NN, &lB[buf][0] + (64 + w * 8) * 64); \
        gload16(gb + (size_t)96 * NN, &lB[buf][0] + (96 + w * 8) * 64); \
    }

    const int pr = t >> 2;
    const int pc = (t & 3) * 16;
    const float ssr = s_src[b * NN + i0 + pr] + a_bp[0];
    const float* Ap  = A + ((size_t)(b * NN + i0 + pr)) * NN + pc;
    const float* sdp = s_dst + b * NN + pc;
    const int ch0 = pc >> 3;
    const int sw0 = ((ch0    ) ^ (pr & 7)) * 8;
    const int sw1 = ((ch0 + 1) ^ (pr & 7)) * 8;
    __bf16* lProw = &lP[0][0] + pr * 64;

    float4 a0E, a1E, a2E, a3E, d0E, d1E, d2E, d3E;
    float4 a0O, a1O, a2O, a3O, d0O, d1O, d2O, d3O;
#define LOADP(step, S) { \
        const float* ap = Ap  + (step) * 64; \
        const float* dp = sdp + (step) * 64; \
        a0##S = *(const float4*)(ap + 0);  a1##S = *(const float4*)(ap + 4); \
        a2##S = *(const float4*)(ap + 8);  a3##S = *(const float4*)(ap + 12); \
        d0##S = *(const float4*)(dp + 0);  d1##S = *(const float4*)(dp + 4); \
        d2##S = *(const float4*)(dp + 8);  d3##S = *(const float4*)(dp + 12); \
    }
#define PB1(vv, idx, av, dv) { \
        float e = ssr + dv; e = e > 0.f ? e : NEG_SLOPE * e; \
        vv[idx] = (__bf16)(av * __expf(e)); }
#define PBUILD(buf, S) { \
        bf16x8 v0, v1; \
        PB1(v0, 0, a0##S.x, d0##S.x) PB1(v0, 1, a0##S.y, d0##S.y) \
        PB1(v0, 2, a0##S.z, d0##S.z) PB1(v0, 3, a0##S.w, d0##S.w) \
        PB1(v0, 4, a1##S.x, d1##S.x) PB1(v0, 5, a1##S.y, d1##S.y) \
        PB1(v0, 6, a1##S.z, d1##S.z) PB1(v0, 7, a1##S.w, d1##S.w) \
        PB1(v1, 0, a2##S.x, d2##S.x) PB1(v1, 1, a2##S.y, d2##S.y) \
        PB1(v1, 2, a2##S.z, d2##S.z) PB1(v1, 3, a2##S.w, d2##S.w) \
        PB1(v1, 4, a3##S.x, d3##S.x) PB1(v1, 5, a3##S.y, d3##S.y) \
        PB1(v1, 6, a3##S.z, d3##S.z) PB1(v1, 7, a3##S.w, d3##S.w) \
        *(bf16x8*)(lProw + (buf) * 4096 + sw0) = v0; \
        *(bf16x8*)(lProw + (buf) * 4096 + sw1) = v1; \
    }

#define MFMA_BLOCK(cur) { \
        const __bf16* lPc = &lP[cur][0]; \
        const __bf16* lBc = &lB[cur][0]; \
        _Pragma("unroll") \
        for (int ks = 0; ks < 2; ++ks) { \
            const int kof = (ks * 32 + quad * 8) ^ swz; \
            bf16x8 pa0 = *(const bf16x8*)(lPc + (wr * 32 + m) * 64 + kof); \
            bf16x8 pa1 = *(const bf16x8*)(lPc + (wr * 32 + 16 + m) * 64 + kof); \
            _Pragma("unroll") \
            for (int n = 0; n < 4; ++n) { \
                bf16x8 bfr = *(const bf16x8*)(lBc + (wc * 64 + n * 16 + m) * 64 + kof); \
                acc[0][n] = __builtin_amdgcn_mfma_f32_16x16x32_bf16(pa0, bfr, acc[0][n], 0, 0, 0); \
                acc[1][n] = __builtin_amdgcn_mfma_f32_16x16x32_bf16(pa1, bfr, acc[1][n], 0, 0, 0); \
            } \
        } \
    }

    // prologue: step-0 regs -> E, build lP[0]; step-1 regs -> O; stage B step 0
    LOADP(0, E)
    STAGEB(0, 0)
    PBUILD(0, E)
    LOADP(1, O)

    f32x4 acc[2][4];
#pragma unroll
    for (int mi = 0; mi < 2; ++mi)
#pragma unroll
        for (int n = 0; n < 4; ++n) acc[mi][n] = (f32x4){0.f, 0.f, 0.f, 0.f};

    const int swz = (m & 7) * 8;
    for (int kt2 = 0; kt2 < 16; ++kt2) {
        const int kt = kt2 * 2;
        // ---- even step kt (cur = 0) ----
        __syncthreads();                    // lP[0], lB[0] staged
        if (kt2 < 15) LOADP(kt + 2, E)      // issue A/sd for step kt+2
        STAGEB(1, kt + 1)                   // stage B for step kt+1
        MFMA_BLOCK(0)
        PBUILD(1, O)                        // build P(kt+1) from O
        // ---- odd step kt+1 (cur = 1) ----
        __syncthreads();                    // lP[1], lB[1] staged
        if (kt2 < 15) {
            LOADP(kt + 3, O)                // issue A/sd for step kt+3
            STAGEB(0, kt + 2)               // stage B for step kt+2
        }
        MFMA_BLOCK(1)
        if (kt2 < 15) PBUILD(0, E)          // build P(kt+2) from E
    }

#pragma unroll
    for (int mi = 0; mi < 2; ++mi)
#pragma unroll
        for (int n = 0; n < 4; ++n) {
            int o = o0 + wc * 64 + n * 16 + m;
#pragma unroll
            for (int rr = 0; rr < 4; ++rr) {
                int orow = i0 + wr * 32 + mi * 16 + quad * 4 + rr;
                out[((size_t)b * NN + orow) * FD + o] = acc[mi][n][rr];
            }
        }
#undef STAGEB
#undef LOADP
#undef PB1
#undef PBUILD
#undef MFMA_BLOCK
}

extern "C" void kernel_launch(void* const* d_in, const int* in_sizes, int n_in,
                              void* d_out, int out_size, void* d_ws, size_t ws_size,
                              hipStream_t stream) {
    const float* A   = (const float*)d_in[0];
    const float* x   = (const float*)d_in[1];
    const float* W   = (const float*)d_in[2];
    const float* a_w = (const float*)d_in[3];
    const float* a_b = (const float*)d_in[4];
    float* out = (float*)d_out;

    char* ws = (char*)d_ws;
    __bf16* WT      = (__bf16*)ws;                      // 131,072 B
    float*  Wh      = (float*)(ws + 131072);            // 16,777,216 B
    __bf16* WhT     = (__bf16*)(ws + 16908288);         // 8,388,608 B
    float*  s_src   = (float*)(ws + 25296896);          // 65,536 B
    float*  s_dst   = (float*)(ws + 25362432);          // 65,536 B
    float*  den_part= (float*)(ws + 25427968);          // 4,194,304 B
                                                        // total = 29,622,272 B (proven)

    k1_prep<<<256, 256, 0, stream>>>(W, WT);
    k2_whgemm<<<512, 256, 0, stream>>>(x, WT, a_w, Wh, s_src, s_dst);
    k4_den<<<1024, 256, 0, stream>>>(A, s_src, s_dst, a_b, den_part);
    k5_wht<<<dim3(32, 4, 8), 256, 0, stream>>>(Wh, den_part, WhT);
    k6f<<<512, 256, 0, stream>>>(A, WhT, s_src, s_dst, a_b, out);
}